// Round 3
// baseline (264.106 us; speedup 1.0000x reference)
//
#include <hip/hip_runtime.h>

#define BB 4
#define SS 1024
#define DD 1024
#define HH 16
#define DKK 64
#define MM (BB*SS)   // 4096

typedef __bf16 bf16;
typedef __bf16 bf16x8 __attribute__((ext_vector_type(8)));
typedef float f32x4 __attribute__((ext_vector_type(4)));

__device__ __forceinline__ f32x4 mfma16(bf16x8 a, bf16x8 b, f32x4 c) {
  return __builtin_amdgcn_mfma_f32_16x16x32_bf16(a, b, c, 0, 0, 0);
}

__device__ __forceinline__ float fexp2(float x) {
  return __builtin_amdgcn_exp2f(x);
}

// ---------------- mask -> bitmask ----------------
__global__ __launch_bounds__(256) void k_mask_bits(const int* __restrict__ mask,
                                                   unsigned* __restrict__ bits) {
  const int row = blockIdx.x;
  const int tid = threadIdx.x;
  const int lane = tid & 63, wv = tid >> 6;
#pragma unroll
  for (int it = 0; it < 4; ++it) {
    const int base = it * 256 + wv * 64;
    const int col = base + lane;
    unsigned long long bal = __ballot(mask[(size_t)row * SS + col] != 0);
    if (lane == 0) {
      bits[(size_t)row * 32 + (base >> 5)] = (unsigned)bal;
      bits[(size_t)row * 32 + (base >> 5) + 1] = (unsigned)(bal >> 32);
    }
  }
}

// ---------------- GEMM  C = (A @ W^T) * oscale ----------------
template<int AF32, int CF32>
__device__ __forceinline__ void gemm_body(const void* __restrict__ Ap,
                                          const float* __restrict__ Wp,
                                          void* __restrict__ Cp,
                                          int Mtot, int N, int K, int blk,
                                          float oscale) {
  __shared__ bf16 Al[128 * 40];
  __shared__ bf16 Bl[128 * 40];
  const int tid = threadIdx.x;
  const int lane = tid & 63;
  const int l15 = lane & 15, l4 = lane >> 4;
  const int wv = tid >> 6;
  const int nbm = Mtot >> 7;
  const int bm = blk % nbm, bn = blk / nbm;
  const size_t m0 = (size_t)bm << 7, n0 = (size_t)bn << 7;
  const int wr = (wv >> 1) << 6, wc = (wv & 1) << 6;
  const int srow = tid >> 2, scol = (tid & 3) << 3;

  f32x4 acc[4][4];
#pragma unroll
  for (int i = 0; i < 4; ++i)
#pragma unroll
    for (int j = 0; j < 4; ++j) acc[i][j] = f32x4{0.f, 0.f, 0.f, 0.f};

  for (int k0 = 0; k0 < K; k0 += 32) {
#pragma unroll
    for (int c = 0; c < 2; ++c) {
      const int row = (c << 6) + srow;
      bf16x8 av;
      if (AF32) {
        const float* s = (const float*)Ap + (m0 + row) * (size_t)K + k0 + scol;
        f32x4 v0 = *(const f32x4*)s;
        f32x4 v1 = *(const f32x4*)(s + 4);
#pragma unroll
        for (int j = 0; j < 4; ++j) { av[j] = (bf16)v0[j]; av[4 + j] = (bf16)v1[j]; }
      } else {
        av = *(const bf16x8*)((const bf16*)Ap + (m0 + row) * (size_t)K + k0 + scol);
      }
      *(bf16x8*)&Al[row * 40 + scol] = av;

      const float* ws_ = Wp + (n0 + row) * (size_t)K + k0 + scol;
      f32x4 w0 = *(const f32x4*)ws_;
      f32x4 w1 = *(const f32x4*)(ws_ + 4);
      bf16x8 wv8;
#pragma unroll
      for (int j = 0; j < 4; ++j) { wv8[j] = (bf16)w0[j]; wv8[4 + j] = (bf16)w1[j]; }
      *(bf16x8*)&Bl[row * 40 + scol] = wv8;
    }
    __syncthreads();

    bf16x8 af[4], bfv[4];
#pragma unroll
    for (int t = 0; t < 4; ++t) {
      af[t]  = *(const bf16x8*)&Al[(wr + t * 16 + l15) * 40 + l4 * 8];
      bfv[t] = *(const bf16x8*)&Bl[(wc + t * 16 + l15) * 40 + l4 * 8];
    }
    __builtin_amdgcn_s_setprio(1);
#pragma unroll
    for (int mt = 0; mt < 4; ++mt)
#pragma unroll
      for (int nt = 0; nt < 4; ++nt)
        acc[mt][nt] = mfma16(af[mt], bfv[nt], acc[mt][nt]);
    __builtin_amdgcn_s_setprio(0);
    __syncthreads();
  }

#pragma unroll
  for (int mt = 0; mt < 4; ++mt)
#pragma unroll
    for (int nt = 0; nt < 4; ++nt)
#pragma unroll
      for (int r = 0; r < 4; ++r) {
        const size_t row = m0 + wr + mt * 16 + l4 * 4 + r;
        const size_t col = n0 + wc + nt * 16 + l15;
        if (CF32) ((float*)Cp)[row * N + col] = acc[mt][nt][r];
        else      ((bf16*)Cp)[row * N + col] = (bf16)(acc[mt][nt][r] * oscale);
      }
}

// Q is pre-scaled by 1/sqrt(dk) * log2(e) so attention works in exp2 domain.
#define QSCALE 0.1803368801111204f

__global__ __launch_bounds__(256)
void k_gemm_qkv(const float* __restrict__ A0, const float* __restrict__ A1,
                const float* __restrict__ A2, const float* __restrict__ W0,
                const float* __restrict__ W1, const float* __restrict__ W2,
                bf16* __restrict__ C0, bf16* __restrict__ C1, bf16* __restrict__ C2) {
  const int z = blockIdx.z;
  const float* A = (z == 0) ? A0 : (z == 1) ? A1 : A2;
  const float* W = (z == 0) ? W0 : (z == 1) ? W1 : W2;
  bf16* C = (z == 0) ? C0 : (z == 1) ? C1 : C2;
  const float sc = (z == 0) ? QSCALE : 1.0f;
  gemm_body<1, 0>(A, W, C, MM, DD, DD, blockIdx.x, sc);
}

__global__ __launch_bounds__(256)
void k_gemm_out(const bf16* __restrict__ A, const float* __restrict__ W,
                float* __restrict__ C) {
  gemm_body<0, 1>(A, W, C, MM, DD, DD, blockIdx.x, 1.0f);
}

// ---------------- flash attention ----------------
#define VSTR 66
__global__ __launch_bounds__(256)
void k_attn(const bf16* __restrict__ Qw, const bf16* __restrict__ Kw,
            const bf16* __restrict__ Vw, const unsigned* __restrict__ mb,
            bf16* __restrict__ Xw) {
  __shared__ bf16 Vl[2][64 * VSTR];   // [buf][d][k], stride 66 (odd dwords)
  __shared__ bf16 Pl[4][16 * VSTR];   // per-wave [q][k]
  const int tid = threadIdx.x, lane = tid & 63, wv = tid >> 6;
  const int l15 = lane & 15, l4 = lane >> 4;
  const int qt = blockIdx.x & 15;
  const int bh = blockIdx.x >> 4;
  const int h = bh & 15, b = bh >> 4;
  const int q0 = qt * 64 + wv * 16;

  const bf16* Qb = Qw + (size_t)(b * SS + q0 + l15) * DD + h * 64;
  bf16x8 qf[2];
  qf[0] = *(const bf16x8*)(Qb + l4 * 8);
  qf[1] = *(const bf16x8*)(Qb + 32 + l4 * 8);

  const bf16* Kb = Kw + (size_t)b * SS * DD + h * 64;
  const bf16* Vb = Vw + (size_t)b * SS * DD + h * 64;
  const unsigned* mrow = mb + (size_t)(b * SS + q0 + l4 * 4) * 32;

  f32x4 acco[4];
#pragma unroll
  for (int dt = 0; dt < 4; ++dt) acco[dt] = f32x4{0.f, 0.f, 0.f, 0.f};
  float mx[4], ssum[4];
#pragma unroll
  for (int r = 0; r < 4; ++r) { mx[r] = -1e30f; ssum[r] = 0.f; }

  bf16* Pw = &Pl[wv][0];
  const int vd = tid & 63, vkb = tid >> 6;

  // prologue: stage V(0) into buf0; issue loads for V(1)
  bf16 vr[16];
#pragma unroll
  for (int i = 0; i < 16; ++i) vr[i] = Vb[(size_t)(i * 4 + vkb) * DD + vd];
#pragma unroll
  for (int i = 0; i < 16; ++i) Vl[0][vd * VSTR + i * 4 + vkb] = vr[i];
#pragma unroll
  for (int i = 0; i < 16; ++i) vr[i] = Vb[(size_t)(64 + i * 4 + vkb) * DD + vd];
  __syncthreads();

  for (int t = 0; t < 16; ++t) {
    const int kv = t * 64;
    // (a) store V(t+1) regs -> buf[(t+1)&1]
    if (t + 1 < 16) {
#pragma unroll
      for (int i = 0; i < 16; ++i)
        Vl[(t + 1) & 1][vd * VSTR + i * 4 + vkb] = vr[i];
    }
    // (b) issue loads for V(t+2)
    if (t + 2 < 16) {
#pragma unroll
      for (int i = 0; i < 16; ++i)
        vr[i] = Vb[(size_t)(kv + 128 + i * 4 + vkb) * DD + vd];
    }
    // (c) QK^T from global K (scores in log2 domain via QSCALE)
    f32x4 sc[4];
    __builtin_amdgcn_s_setprio(1);
#pragma unroll
    for (int st = 0; st < 4; ++st) {
      const bf16* kp = Kb + (size_t)(kv + st * 16 + l15) * DD;
      bf16x8 kf0 = *(const bf16x8*)(kp + l4 * 8);
      bf16x8 kf1 = *(const bf16x8*)(kp + 32 + l4 * 8);
      f32x4 s = f32x4{0.f, 0.f, 0.f, 0.f};
      s = mfma16(qf[0], kf0, s);
      s = mfma16(qf[1], kf1, s);
      sc[st] = s;
    }
    __builtin_amdgcn_s_setprio(0);
    // mask
    float val[4][4];
#pragma unroll
    for (int r = 0; r < 4; ++r) {
      const uint2 m2 = *(const uint2*)&mrow[r * 32 + (kv >> 5)];
#pragma unroll
      for (int st = 0; st < 4; ++st) {
        const unsigned w = (st < 2) ? m2.x : m2.y;
        const int bit = (w >> (l15 + ((st & 1) << 4))) & 1;
        val[st][r] = bit ? sc[st][r] : -1e9f;
      }
    }
    // online softmax (exp2 domain)
#pragma unroll
    for (int r = 0; r < 4; ++r) {
      float rm = fmaxf(fmaxf(val[0][r], val[1][r]), fmaxf(val[2][r], val[3][r]));
#pragma unroll
      for (int off = 1; off <= 8; off <<= 1) rm = fmaxf(rm, __shfl_xor(rm, off));
      const float mn = fmaxf(mx[r], rm);
      const float scal = fexp2(mx[r] - mn);
      mx[r] = mn;
      ssum[r] *= scal;
#pragma unroll
      for (int dt = 0; dt < 4; ++dt) acco[dt][r] *= scal;
#pragma unroll
      for (int st = 0; st < 4; ++st) {
        const float p = fexp2(val[st][r] - mn);
        ssum[r] += p;
        Pw[(l4 * 4 + r) * VSTR + st * 16 + l15] = (bf16)p;
      }
    }
    // (d) PV from buf[t&1]
    const bf16* Vc = &Vl[t & 1][0];
    __builtin_amdgcn_s_setprio(1);
#pragma unroll
    for (int kk = 0; kk < 2; ++kk) {
      bf16x8 pa = *(const bf16x8*)&Pw[l15 * VSTR + kk * 32 + l4 * 8];
#pragma unroll
      for (int dt = 0; dt < 4; ++dt) {
        bf16x8 vb = *(const bf16x8*)&Vc[(dt * 16 + l15) * VSTR + kk * 32 + l4 * 8];
        acco[dt] = mfma16(pa, vb, acco[dt]);
      }
    }
    __builtin_amdgcn_s_setprio(0);
    __syncthreads();
  }

#pragma unroll
  for (int r = 0; r < 4; ++r) {
#pragma unroll
    for (int off = 1; off <= 8; off <<= 1) ssum[r] += __shfl_xor(ssum[r], off);
  }
#pragma unroll
  for (int r = 0; r < 4; ++r) {
    const float inv = 1.0f / ssum[r];
#pragma unroll
    for (int dt = 0; dt < 4; ++dt) {
      Xw[(size_t)(b * SS + q0 + l4 * 4 + r) * DD + h * 64 + dt * 16 + l15] =
          (bf16)(acco[dt][r] * inv);
    }
  }
}

// ---------------- launch ----------------
extern "C" void kernel_launch(void* const* d_in, const int* in_sizes, int n_in,
                              void* d_out, int out_size, void* d_ws, size_t ws_size,
                              hipStream_t stream) {
  const float* q32 = (const float*)d_in[0];
  const float* k32 = (const float*)d_in[1];
  const float* v32 = (const float*)d_in[2];
  const int* mask = (const int*)d_in[3];
  const float* Wq = (const float*)d_in[4];
  const float* Wk = (const float*)d_in[5];
  const float* Wv = (const float*)d_in[6];
  const float* Wo = (const float*)d_in[7];
  float* out = (float*)d_out;

  bf16* Qb = (bf16*)d_ws;
  bf16* Kb = Qb + (size_t)MM * DD;
  bf16* Vb = Kb + (size_t)MM * DD;
  bf16* Xb = Vb + (size_t)MM * DD;
  unsigned* mbits = (unsigned*)(Xb + (size_t)MM * DD);

  k_mask_bits<<<BB * SS, 256, 0, stream>>>(mask, mbits);
  k_gemm_qkv<<<dim3((MM / 128) * (DD / 128), 1, 3), 256, 0, stream>>>(
      q32, k32, v32, Wq, Wk, Wv, Qb, Kb, Vb);
  k_attn<<<BB * HH * (SS / 64), 256, 0, stream>>>(Qb, Kb, Vb, mbits, Xb);
  k_gemm_out<<<(MM / 128) * (DD / 128), 256, 0, stream>>>(Xb, Wo, out);
}

// Round 4
// 169.701 us; speedup vs baseline: 1.5563x; 1.5563x over previous
//
#include <hip/hip_runtime.h>

#define BB 4
#define SS 1024
#define DD 1024
#define HH 16
#define DKK 64
#define MM (BB*SS)   // 4096

typedef __bf16 bf16;
typedef __bf16 bf16x8 __attribute__((ext_vector_type(8)));
typedef float f32x4 __attribute__((ext_vector_type(4)));

__device__ __forceinline__ f32x4 mfma16(bf16x8 a, bf16x8 b, f32x4 c) {
  return __builtin_amdgcn_mfma_f32_16x16x32_bf16(a, b, c, 0, 0, 0);
}

__device__ __forceinline__ float fexp2(float x) {
  return __builtin_amdgcn_exp2f(x);
}

// ---------------- mask -> bitmask ----------------
__global__ __launch_bounds__(256) void k_mask_bits(const int* __restrict__ mask,
                                                   unsigned* __restrict__ bits) {
  const int row = blockIdx.x;
  const int tid = threadIdx.x;
  const int lane = tid & 63, wv = tid >> 6;
#pragma unroll
  for (int it = 0; it < 4; ++it) {
    const int base = it * 256 + wv * 64;
    const int col = base + lane;
    unsigned long long bal = __ballot(mask[(size_t)row * SS + col] != 0);
    if (lane == 0) {
      bits[(size_t)row * 32 + (base >> 5)] = (unsigned)bal;
      bits[(size_t)row * 32 + (base >> 5) + 1] = (unsigned)(bal >> 32);
    }
  }
}

// ---------------- GEMM  C = (A @ W^T) * oscale ----------------
template<int AF32, int CF32>
__device__ __forceinline__ void gemm_body(const void* __restrict__ Ap,
                                          const float* __restrict__ Wp,
                                          void* __restrict__ Cp,
                                          int Mtot, int N, int K, int blk,
                                          float oscale) {
  __shared__ bf16 Al[128 * 40];
  __shared__ bf16 Bl[128 * 40];
  const int tid = threadIdx.x;
  const int lane = tid & 63;
  const int l15 = lane & 15, l4 = lane >> 4;
  const int wv = tid >> 6;
  const int nbm = Mtot >> 7;
  const int bm = blk % nbm, bn = blk / nbm;
  const size_t m0 = (size_t)bm << 7, n0 = (size_t)bn << 7;
  const int wr = (wv >> 1) << 6, wc = (wv & 1) << 6;
  const int srow = tid >> 2, scol = (tid & 3) << 3;

  f32x4 acc[4][4];
#pragma unroll
  for (int i = 0; i < 4; ++i)
#pragma unroll
    for (int j = 0; j < 4; ++j) acc[i][j] = f32x4{0.f, 0.f, 0.f, 0.f};

  for (int k0 = 0; k0 < K; k0 += 32) {
#pragma unroll
    for (int c = 0; c < 2; ++c) {
      const int row = (c << 6) + srow;
      bf16x8 av;
      if (AF32) {
        const float* s = (const float*)Ap + (m0 + row) * (size_t)K + k0 + scol;
        f32x4 v0 = *(const f32x4*)s;
        f32x4 v1 = *(const f32x4*)(s + 4);
#pragma unroll
        for (int j = 0; j < 4; ++j) { av[j] = (bf16)v0[j]; av[4 + j] = (bf16)v1[j]; }
      } else {
        av = *(const bf16x8*)((const bf16*)Ap + (m0 + row) * (size_t)K + k0 + scol);
      }
      *(bf16x8*)&Al[row * 40 + scol] = av;

      const float* ws_ = Wp + (n0 + row) * (size_t)K + k0 + scol;
      f32x4 w0 = *(const f32x4*)ws_;
      f32x4 w1 = *(const f32x4*)(ws_ + 4);
      bf16x8 wv8;
#pragma unroll
      for (int j = 0; j < 4; ++j) { wv8[j] = (bf16)w0[j]; wv8[4 + j] = (bf16)w1[j]; }
      *(bf16x8*)&Bl[row * 40 + scol] = wv8;
    }
    __syncthreads();

    bf16x8 af[4], bfv[4];
#pragma unroll
    for (int t = 0; t < 4; ++t) {
      af[t]  = *(const bf16x8*)&Al[(wr + t * 16 + l15) * 40 + l4 * 8];
      bfv[t] = *(const bf16x8*)&Bl[(wc + t * 16 + l15) * 40 + l4 * 8];
    }
    __builtin_amdgcn_s_setprio(1);
#pragma unroll
    for (int mt = 0; mt < 4; ++mt)
#pragma unroll
      for (int nt = 0; nt < 4; ++nt)
        acc[mt][nt] = mfma16(af[mt], bfv[nt], acc[mt][nt]);
    __builtin_amdgcn_s_setprio(0);
    __syncthreads();
  }

#pragma unroll
  for (int mt = 0; mt < 4; ++mt)
#pragma unroll
    for (int nt = 0; nt < 4; ++nt)
#pragma unroll
      for (int r = 0; r < 4; ++r) {
        const size_t row = m0 + wr + mt * 16 + l4 * 4 + r;
        const size_t col = n0 + wc + nt * 16 + l15;
        if (CF32) ((float*)Cp)[row * N + col] = acc[mt][nt][r];
        else      ((bf16*)Cp)[row * N + col] = (bf16)(acc[mt][nt][r] * oscale);
      }
}

// Q is pre-scaled by 1/sqrt(dk) * log2(e) so attention works in exp2 domain.
#define QSCALE 0.1803368801111204f

__global__ __launch_bounds__(256)
void k_gemm_qkv(const float* __restrict__ A0, const float* __restrict__ A1,
                const float* __restrict__ A2, const float* __restrict__ W0,
                const float* __restrict__ W1, const float* __restrict__ W2,
                bf16* __restrict__ C0, bf16* __restrict__ C1, bf16* __restrict__ C2) {
  const int z = blockIdx.z;
  const float* A = (z == 0) ? A0 : (z == 1) ? A1 : A2;
  const float* W = (z == 0) ? W0 : (z == 1) ? W1 : W2;
  bf16* C = (z == 0) ? C0 : (z == 1) ? C1 : C2;
  const float sc = (z == 0) ? QSCALE : 1.0f;
  gemm_body<1, 0>(A, W, C, MM, DD, DD, blockIdx.x, sc);
}

__global__ __launch_bounds__(256)
void k_gemm_out(const bf16* __restrict__ A, const float* __restrict__ W,
                float* __restrict__ C) {
  gemm_body<0, 1>(A, W, C, MM, DD, DD, blockIdx.x, 1.0f);
}

// ---------------- flash attention, swapped-QK^T in-register softmax -------
// mfma(K,Q): lane (l15,g) holds S[k = st*16 + g*4 + r][q = l15].
// Softmax lane-local + 2 shfl. P redistributed to PV A-frag layout via
// ds_bpermute (src lane = l15 + 16*(2(g&1)+(dw>>1)), src dword 2(g>>1)+(dw&1)).
// LDS: single V buffer [d][k] stride 66 (8448 B) -> 4+ blocks/CU.
#define VSTR 66
__global__ __launch_bounds__(256)
void k_attn(const bf16* __restrict__ Qw, const bf16* __restrict__ Kw,
            const bf16* __restrict__ Vw, const unsigned* __restrict__ mb,
            bf16* __restrict__ Xw) {
  __shared__ bf16 Vl[64 * VSTR];
  const int tid = threadIdx.x, lane = tid & 63, wv = tid >> 6;
  const int l15 = lane & 15, g = lane >> 4, gq4 = g << 2;
  const int qt = blockIdx.x & 15;
  const int bh = blockIdx.x >> 4;
  const int h = bh & 15, b = bh >> 4;
  const int q0 = qt * 64 + wv * 16;

  // Q fragments (B operand): Q[q0+l15][g*8+j]
  const bf16* Qb = Qw + (size_t)(b * SS + q0 + l15) * DD + h * 64;
  bf16x8 qf0 = *(const bf16x8*)(Qb + g * 8);
  bf16x8 qf1 = *(const bf16x8*)(Qb + 32 + g * 8);

  const bf16* Kb = Kw + (size_t)b * SS * DD + h * 64 + g * 8;
  const bf16* Vb = Vw + (size_t)b * SS * DD + h * 64 + l15 * 4;
  const unsigned* mrow = mb + (size_t)(b * SS + q0 + l15) * 32;

  f32x4 acco[4];
#pragma unroll
  for (int dt = 0; dt < 4; ++dt) acco[dt] = f32x4{0.f, 0.f, 0.f, 0.f};
  float mx = -3e38f, ssum = 0.f;

  const int vk0 = wv * 4 + g;               // V stage: k-base for this thread
  const int idxA = (l15 + ((g & 1) << 5)) << 2;
  const int idxB = idxA + 64;

  for (int t = 0; t < 16; ++t) {
    const int kv = t << 6;
    // V global loads (issued first; consumed by LDS stores after barrier)
    union { uint2 u; bf16 h4[4]; } vld[4];
#pragma unroll
    for (int i = 0; i < 4; ++i)
      vld[i].u = *(const uint2*)(Vb + (size_t)(kv + i * 16 + vk0) * DD);
    // K loads (A-frags): K[kv+st*16+l15][g*8..]
    bf16x8 kf[4][2];
#pragma unroll
    for (int st = 0; st < 4; ++st) {
      const bf16* kp = Kb + (size_t)(kv + st * 16 + l15) * DD;
      kf[st][0] = *(const bf16x8*)kp;
      kf[st][1] = *(const bf16x8*)(kp + 32);
    }
    const uint2 m2 = *(const uint2*)&mrow[kv >> 5];
    __syncthreads();                        // barrier1: prev PV reads done
    // stage V transposed: Vl[d][k]
#pragma unroll
    for (int i = 0; i < 4; ++i)
#pragma unroll
      for (int j = 0; j < 4; ++j)
        Vl[(l15 * 4 + j) * VSTR + i * 16 + vk0] = vld[i].h4[j];
    // swapped QK^T: S[k][q]
    f32x4 sc[4];
#pragma unroll
    for (int st = 0; st < 4; ++st) {
      f32x4 s = f32x4{0.f, 0.f, 0.f, 0.f};
      s = mfma16(kf[st][0], qf0, s);
      s = mfma16(kf[st][1], qf1, s);
      sc[st] = s;
    }
    // mask (q = l15 per lane; k = st*16 + g*4 + r)
    float p[4][4];
#pragma unroll
    for (int st = 0; st < 4; ++st) {
      const unsigned w = (st < 2) ? m2.x : m2.y;
#pragma unroll
      for (int r = 0; r < 4; ++r) {
        const int bit = (w >> (((st & 1) << 4) + gq4 + r)) & 1;
        p[st][r] = bit ? sc[st][r] : -1e9f;
      }
    }
    // row max: 16 in-lane + cross-g
    float rm = p[0][0];
#pragma unroll
    for (int st = 0; st < 4; ++st)
#pragma unroll
      for (int r = 0; r < 4; ++r) rm = fmaxf(rm, p[st][r]);
    rm = fmaxf(rm, __shfl_xor(rm, 16));
    rm = fmaxf(rm, __shfl_xor(rm, 32));
    // defer-max (T13): rescale only when max grew by > 8
    if (!__all(rm <= mx + 8.0f)) {
      const float mn = fmaxf(mx, rm);
      const float scal = fexp2(mx - mn);
      mx = mn;
      ssum *= scal;
      const float s0 = __shfl(scal, gq4);
      const float s1 = __shfl(scal, gq4 + 1);
      const float s2 = __shfl(scal, gq4 + 2);
      const float s3 = __shfl(scal, gq4 + 3);
#pragma unroll
      for (int dt = 0; dt < 4; ++dt) {
        acco[dt][0] *= s0; acco[dt][1] *= s1;
        acco[dt][2] *= s2; acco[dt][3] *= s3;
      }
    }
    // exps + partial sum
#pragma unroll
    for (int st = 0; st < 4; ++st)
#pragma unroll
      for (int r = 0; r < 4; ++r) {
        p[st][r] = fexp2(p[st][r] - mx);
        ssum += p[st][r];
      }
    __syncthreads();                        // barrier2: Vl staged
    // PV: redistribute P to A-frag layout, then MFMA
#pragma unroll
    for (int kk = 0; kk < 2; ++kk) {
      union { bf16 h8[8]; int d[4]; } pk;
#pragma unroll
      for (int dd = 0; dd < 4; ++dd) {
        pk.h8[2 * dd]     = (bf16)p[2 * kk + (dd >> 1)][2 * (dd & 1)];
        pk.h8[2 * dd + 1] = (bf16)p[2 * kk + (dd >> 1)][2 * (dd & 1) + 1];
      }
      const int rA0 = __builtin_amdgcn_ds_bpermute(idxA, pk.d[0]);
      const int rA2 = __builtin_amdgcn_ds_bpermute(idxA, pk.d[2]);
      const int rA1 = __builtin_amdgcn_ds_bpermute(idxA, pk.d[1]);
      const int rA3 = __builtin_amdgcn_ds_bpermute(idxA, pk.d[3]);
      const int rB0 = __builtin_amdgcn_ds_bpermute(idxB, pk.d[0]);
      const int rB2 = __builtin_amdgcn_ds_bpermute(idxB, pk.d[2]);
      const int rB1 = __builtin_amdgcn_ds_bpermute(idxB, pk.d[1]);
      const int rB3 = __builtin_amdgcn_ds_bpermute(idxB, pk.d[3]);
      union { bf16x8 v; int d[4]; } pa;
      pa.d[0] = (g >= 2) ? rA2 : rA0;
      pa.d[1] = (g >= 2) ? rA3 : rA1;
      pa.d[2] = (g >= 2) ? rB2 : rB0;
      pa.d[3] = (g >= 2) ? rB3 : rB1;
#pragma unroll
      for (int dt = 0; dt < 4; ++dt) {
        bf16x8 vb = *(const bf16x8*)&Vl[(dt * 16 + l15) * VSTR + kk * 32 + g * 8];
        acco[dt] = mfma16(pa.v, vb, acco[dt]);
      }
    }
  }

  // epilogue: finalize denom (cross-g) and write O[q][d]
  ssum += __shfl_xor(ssum, 16);
  ssum += __shfl_xor(ssum, 32);
  const float inv = 1.0f / ssum;            // valid for q = l15 at every lane
  const float i0 = __shfl(inv, gq4);
  const float i1 = __shfl(inv, gq4 + 1);
  const float i2 = __shfl(inv, gq4 + 2);
  const float i3 = __shfl(inv, gq4 + 3);
#pragma unroll
  for (int dt = 0; dt < 4; ++dt) {
    bf16* xp = Xw + (size_t)(b * SS + q0 + gq4) * DD + h * 64 + dt * 16 + l15;
    xp[0 * DD] = (bf16)(acco[dt][0] * i0);
    xp[1 * DD] = (bf16)(acco[dt][1] * i1);
    xp[2 * DD] = (bf16)(acco[dt][2] * i2);
    xp[3 * DD] = (bf16)(acco[dt][3] * i3);
  }
}

// ---------------- launch ----------------
extern "C" void kernel_launch(void* const* d_in, const int* in_sizes, int n_in,
                              void* d_out, int out_size, void* d_ws, size_t ws_size,
                              hipStream_t stream) {
  const float* q32 = (const float*)d_in[0];
  const float* k32 = (const float*)d_in[1];
  const float* v32 = (const float*)d_in[2];
  const int* mask = (const int*)d_in[3];
  const float* Wq = (const float*)d_in[4];
  const float* Wk = (const float*)d_in[5];
  const float* Wv = (const float*)d_in[6];
  const float* Wo = (const float*)d_in[7];
  float* out = (float*)d_out;

  bf16* Qb = (bf16*)d_ws;
  bf16* Kb = Qb + (size_t)MM * DD;
  bf16* Vb = Kb + (size_t)MM * DD;
  bf16* Xb = Vb + (size_t)MM * DD;
  unsigned* mbits = (unsigned*)(Xb + (size_t)MM * DD);

  k_mask_bits<<<BB * SS, 256, 0, stream>>>(mask, mbits);
  k_gemm_qkv<<<dim3((MM / 128) * (DD / 128), 1, 3), 256, 0, stream>>>(
      q32, k32, v32, Wq, Wk, Wv, Qb, Kb, Vb);
  k_attn<<<BB * HH * (SS / 64), 256, 0, stream>>>(Qb, Kb, Vb, mbits, Xb);
  k_gemm_out<<<(MM / 128) * (DD / 128), 256, 0, stream>>>(Xb, Wo, out);
}